// Round 1
// baseline (1849.286 us; speedup 1.0000x reference)
//
#include <hip/hip_runtime.h>
#include <cstdint>

#define H 64

// ---------- helpers ----------

// Monotone float->uint encoding so atomicMax(uint) == float max.
__device__ __forceinline__ unsigned int enc_f(float f) {
  unsigned int u = __float_as_uint(f);
  return (u & 0x80000000u) ? ~u : (u | 0x80000000u);
}
__device__ __forceinline__ float dec_f(unsigned int u) {
  return __uint_as_float((u & 0x80000000u) ? (u ^ 0x80000000u) : ~u);
}

__device__ __forceinline__ float selu_f(float x) {
  const float sc = 1.0507009873554805f;
  const float al = 1.6732632423543772f;
  return x > 0.f ? sc * x : sc * al * (expf(x) - 1.f);
}

// ---------- GEMM: C[N x 64] = A[N x 64] @ W[64 x 64] + b ----------
// Block: 256 threads = 64 rows x 4 col-groups(16 cols each).
// W (16KB) + 64-row A tile (stride 65, conflict-free) in LDS.
__global__ __launch_bounds__(256) void gemm64(
    const float* __restrict__ A, const float* __restrict__ W,
    const float* __restrict__ bvec, float* __restrict__ C, int N) {
  __shared__ float Ws[64 * 64];
  __shared__ float As[64][65];
  __shared__ float bs[64];

  const int tid = threadIdx.x;
  for (int i = tid; i < 1024; i += 256) {
    ((float4*)Ws)[i] = ((const float4*)W)[i];
  }
  if (tid < 64) bs[tid] = bvec[tid];

  const int row0 = blockIdx.x * 64;
  for (int i = tid; i < 1024; i += 256) {  // 64 rows * 16 float4
    int r = i >> 4, c4 = i & 15;
    int row = row0 + r;
    float4 v = make_float4(0.f, 0.f, 0.f, 0.f);
    if (row < N) v = ((const float4*)(A + (size_t)row * H))[c4];
    As[r][c4 * 4 + 0] = v.x;
    As[r][c4 * 4 + 1] = v.y;
    As[r][c4 * 4 + 2] = v.z;
    As[r][c4 * 4 + 3] = v.w;
  }
  __syncthreads();

  const int g = tid & 3;   // col group (16 cols)
  const int r = tid >> 2;  // row within tile [0,64)
  float acc[16];
#pragma unroll
  for (int j = 0; j < 16; ++j) acc[j] = bs[g * 16 + j];

  for (int k = 0; k < 64; ++k) {
    float ak = As[r][k];
    const float4* wrow = (const float4*)&Ws[k * 64 + g * 16];
#pragma unroll
    for (int j4 = 0; j4 < 4; ++j4) {
      float4 w = wrow[j4];
      acc[j4 * 4 + 0] += ak * w.x;
      acc[j4 * 4 + 1] += ak * w.y;
      acc[j4 * 4 + 2] += ak * w.z;
      acc[j4 * 4 + 3] += ak * w.w;
    }
  }

  const int row = row0 + r;
  if (row < N) {
    float4* crow = (float4*)(C + (size_t)row * H + g * 16);
    crow[0] = make_float4(acc[0], acc[1], acc[2], acc[3]);
    crow[1] = make_float4(acc[4], acc[5], acc[6], acc[7]);
    crow[2] = make_float4(acc[8], acc[9], acc[10], acc[11]);
    crow[3] = make_float4(acc[12], acc[13], acc[14], acc[15]);
  }
}

// ---------- per-edge score + segment max ----------
// thread-per-edge; edges >= E_real are self-loops (src=dst=e-E_real)
__global__ __launch_bounds__(256) void edge_score(
    const int* __restrict__ esrc, const int* __restrict__ edst,
    int E_real, int n_edges,
    const float* __restrict__ xl, const float* __restrict__ xr,
    const float* __restrict__ att, float* __restrict__ sc,
    unsigned int* __restrict__ mmax) {
  int e = blockIdx.x * 256 + threadIdx.x;
  if (e >= n_edges) return;
  int s, d;
  if (e < E_real) {
    s = esrc[e];
    d = edst[e];
  } else {
    s = e - E_real;
    d = s;
  }
  const float4* pl = (const float4*)(xl + (size_t)s * H);
  const float4* pr = (const float4*)(xr + (size_t)d * H);
  const float4* pa = (const float4*)att;
  float sum = 0.f;
#pragma unroll
  for (int i = 0; i < H / 4; ++i) {
    float4 a = pl[i], b = pr[i], t = pa[i];
    float v;
    v = a.x + b.x; v = v > 0.f ? v : 0.2f * v; sum += v * t.x;
    v = a.y + b.y; v = v > 0.f ? v : 0.2f * v; sum += v * t.y;
    v = a.z + b.z; v = v > 0.f ? v : 0.2f * v; sum += v * t.z;
    v = a.w + b.w; v = v > 0.f ? v : 0.2f * v; sum += v * t.w;
  }
  sc[e] = sum;
  atomicMax(&mmax[d], enc_f(sum));
}

// ---------- per-edge exp + denominator + weighted scatter ----------
// one 64-lane wave per edge (block = 4 edges); lane h handles feature h
__global__ __launch_bounds__(256) void edge_accum(
    const int* __restrict__ esrc, const int* __restrict__ edst,
    int E_real, int n_edges,
    const float* __restrict__ xl, const float* __restrict__ sc,
    const unsigned int* __restrict__ mmax,
    float* __restrict__ ssum, float* __restrict__ acc) {
  int e = blockIdx.x * 4 + (threadIdx.x >> 6);
  if (e >= n_edges) return;
  int h = threadIdx.x & 63;
  int s, d;
  if (e < E_real) {
    s = esrc[e];
    d = edst[e];
  } else {
    s = e - E_real;
    d = s;
  }
  float ex = __expf(sc[e] - dec_f(mmax[d]));
  if (h == 0) atomicAdd(&ssum[d], ex);
  atomicAdd(&acc[(size_t)d * H + h], ex * xl[(size_t)s * H + h]);
}

// ---------- normalize + bias + selu ----------
__global__ __launch_bounds__(256) void finalize_k(
    const float* __restrict__ acc, const float* __restrict__ ssum,
    const float* __restrict__ bias, float* __restrict__ out, int n) {
  int idx = blockIdx.x * 256 + threadIdx.x;
  if (idx >= n * H) return;
  int d = idx >> 6, h = idx & 63;
  float v = acc[idx] / (ssum[d] + 1e-16f) + bias[h];
  out[idx] = selu_f(v);
}

// ---------- launch ----------
extern "C" void kernel_launch(void* const* d_in, const int* in_sizes, int n_in,
                              void* d_out, int out_size, void* d_ws, size_t ws_size,
                              hipStream_t stream) {
  const float* x_user = (const float*)d_in[0];
  const float* x_movie = (const float*)d_in[1];
  const int* e_u2m = (const int*)d_in[2];
  const int* e_m2u = (const int*)d_in[3];
  const float* Wl = (const float*)d_in[4];
  const float* bl = (const float*)d_in[5];
  const float* Wr = (const float*)d_in[6];
  const float* br = (const float*)d_in[7];
  const float* att = (const float*)d_in[8];
  const float* bias = (const float*)d_in[9];

  const int n_user = in_sizes[0] / H;
  const int n_movie = in_sizes[1] / H;
  const int E1 = in_sizes[2] / 2;  // user->movie edges
  const int E2 = in_sizes[3] / 2;  // movie->user edges
  const int n_loop = n_user < n_movie ? n_user : n_movie;

  float* ws = (float*)d_ws;
  size_t o = 0;
  float* xl_u2m = ws + o; o += (size_t)n_user * H;
  float* xr_u2m = ws + o; o += (size_t)n_movie * H;
  float* xl_m2u = ws + o; o += (size_t)n_movie * H;
  float* xr_m2u = ws + o; o += (size_t)n_user * H;
  // zero-init region (contiguous): acc_m, acc_u, mmax_m, ssum_m, mmax_u, ssum_u
  size_t zero_base = o;
  float* acc_m = ws + o; o += (size_t)n_movie * H;
  float* acc_u = ws + o; o += (size_t)n_user * H;
  unsigned int* mmax_m = (unsigned int*)(ws + o); o += n_movie;
  float* ssum_m = ws + o; o += n_movie;
  unsigned int* mmax_u = (unsigned int*)(ws + o); o += n_user;
  float* ssum_u = ws + o; o += n_user;
  const size_t zero_bytes = (o - zero_base) * sizeof(float);
  float* sc1 = ws + o; o += (size_t)(E1 + n_loop);
  float* sc2 = ws + o; o += (size_t)(E2 + n_loop);

  float* out_u = (float*)d_out;
  float* out_m = out_u + (size_t)n_user * H;

  const int gu = (n_user + 63) / 64;
  const int gm = (n_movie + 63) / 64;
  const int nE1 = E1 + n_loop;
  const int nE2 = E2 + n_loop;

  for (int l = 0; l < 2; ++l) {
    const float* cu = (l == 0) ? x_user : out_u;
    const float* cm = (l == 0) ? x_movie : out_m;
    const int p0 = l * 2 + 0;  // user->movie params
    const int p1 = l * 2 + 1;  // movie->user params

    hipMemsetAsync(ws + zero_base, 0, zero_bytes, stream);

    gemm64<<<gu, 256, 0, stream>>>(cu, Wl + (size_t)p0 * H * H, bl + (size_t)p0 * H, xl_u2m, n_user);
    gemm64<<<gm, 256, 0, stream>>>(cm, Wr + (size_t)p0 * H * H, br + (size_t)p0 * H, xr_u2m, n_movie);
    gemm64<<<gm, 256, 0, stream>>>(cm, Wl + (size_t)p1 * H * H, bl + (size_t)p1 * H, xl_m2u, n_movie);
    gemm64<<<gu, 256, 0, stream>>>(cu, Wr + (size_t)p1 * H * H, br + (size_t)p1 * H, xr_m2u, n_user);

    // user -> movie (dst = movie)
    edge_score<<<(nE1 + 255) / 256, 256, 0, stream>>>(
        e_u2m, e_u2m + E1, E1, nE1, xl_u2m, xr_u2m, att + (size_t)p0 * H, sc1, mmax_m);
    edge_accum<<<(nE1 + 3) / 4, 256, 0, stream>>>(
        e_u2m, e_u2m + E1, E1, nE1, xl_u2m, sc1, mmax_m, ssum_m, acc_m);
    finalize_k<<<((n_movie * H) + 255) / 256, 256, 0, stream>>>(
        acc_m, ssum_m, bias + (size_t)p0 * H, out_m, n_movie);

    // movie -> user (dst = user)
    edge_score<<<(nE2 + 255) / 256, 256, 0, stream>>>(
        e_m2u, e_m2u + E2, E2, nE2, xl_m2u, xr_m2u, att + (size_t)p1 * H, sc2, mmax_u);
    edge_accum<<<(nE2 + 3) / 4, 256, 0, stream>>>(
        e_m2u, e_m2u + E2, E2, nE2, xl_m2u, sc2, mmax_u, ssum_u, acc_u);
    finalize_k<<<((n_user * H) + 255) / 256, 256, 0, stream>>>(
        acc_u, ssum_u, bias + (size_t)p1 * H, out_u, n_user);
  }
}

// Round 2
// 1015.817 us; speedup vs baseline: 1.8205x; 1.8205x over previous
//
#include <hip/hip_runtime.h>
#include <cstdint>

#define H 64

__device__ __forceinline__ float selu_f(float x) {
  const float sc = 1.0507009873554805f;
  const float al = 1.6732632423543772f;
  return x > 0.f ? sc * x : sc * al * (expf(x) - 1.f);
}

// ---------- GEMM: C[N x 64] = A[N x 64] @ W[64 x 64] + b ----------
__global__ __launch_bounds__(256) void gemm64(
    const float* __restrict__ A, const float* __restrict__ W,
    const float* __restrict__ bvec, float* __restrict__ C, int N) {
  __shared__ float Ws[64 * 64];
  __shared__ float As[64][65];
  __shared__ float bs[64];

  const int tid = threadIdx.x;
  for (int i = tid; i < 1024; i += 256) {
    ((float4*)Ws)[i] = ((const float4*)W)[i];
  }
  if (tid < 64) bs[tid] = bvec[tid];

  const int row0 = blockIdx.x * 64;
  for (int i = tid; i < 1024; i += 256) {
    int r = i >> 4, c4 = i & 15;
    int row = row0 + r;
    float4 v = make_float4(0.f, 0.f, 0.f, 0.f);
    if (row < N) v = ((const float4*)(A + (size_t)row * H))[c4];
    As[r][c4 * 4 + 0] = v.x;
    As[r][c4 * 4 + 1] = v.y;
    As[r][c4 * 4 + 2] = v.z;
    As[r][c4 * 4 + 3] = v.w;
  }
  __syncthreads();

  const int g = tid & 3;
  const int r = tid >> 2;
  float acc[16];
#pragma unroll
  for (int j = 0; j < 16; ++j) acc[j] = bs[g * 16 + j];

  for (int k = 0; k < 64; ++k) {
    float ak = As[r][k];
    const float4* wrow = (const float4*)&Ws[k * 64 + g * 16];
#pragma unroll
    for (int j4 = 0; j4 < 4; ++j4) {
      float4 w = wrow[j4];
      acc[j4 * 4 + 0] += ak * w.x;
      acc[j4 * 4 + 1] += ak * w.y;
      acc[j4 * 4 + 2] += ak * w.z;
      acc[j4 * 4 + 3] += ak * w.w;
    }
  }

  const int row = row0 + r;
  if (row < N) {
    float4* crow = (float4*)(C + (size_t)row * H + g * 16);
    crow[0] = make_float4(acc[0], acc[1], acc[2], acc[3]);
    crow[1] = make_float4(acc[4], acc[5], acc[6], acc[7]);
    crow[2] = make_float4(acc[8], acc[9], acc[10], acc[11]);
    crow[3] = make_float4(acc[12], acc[13], acc[14], acc[15]);
  }
}

// ---------- CSR build ----------
__global__ __launch_bounds__(256) void hist_k(
    const int* __restrict__ edst, int E_real, int n_edges, int* __restrict__ cnt) {
  int e = blockIdx.x * 256 + threadIdx.x;
  if (e >= n_edges) return;
  int d = (e < E_real) ? edst[e] : (e - E_real);
  atomicAdd(&cnt[d], 1);
}

__global__ __launch_bounds__(256) void scan_partial(
    const int* __restrict__ cnt, int n, int* __restrict__ psum, int* __restrict__ bsum) {
  __shared__ int sh[256];
  int i = blockIdx.x * 256 + threadIdx.x;
  int tid = threadIdx.x;
  sh[tid] = (i < n) ? cnt[i] : 0;
  __syncthreads();
  for (int off = 1; off < 256; off <<= 1) {
    int t = (tid >= off) ? sh[tid - off] : 0;
    __syncthreads();
    if (tid >= off) sh[tid] += t;
    __syncthreads();
  }
  if (i < n) psum[i] = sh[tid];
  if (tid == 255) bsum[blockIdx.x] = sh[255];
}

__global__ void scan_bsums(int* __restrict__ bsum, int nb) {
  if (threadIdx.x == 0 && blockIdx.x == 0) {
    int run = 0;
    for (int b = 0; b < nb; ++b) { int t = bsum[b]; bsum[b] = run; run += t; }
  }
}

// row_ptr[i+1] = inclusive_scan(cnt)[i]; wofs[i] = exclusive offset (write cursor)
__global__ __launch_bounds__(256) void finalize_scan(
    const int* __restrict__ cnt, const int* __restrict__ psum,
    const int* __restrict__ bsum, int n, int* __restrict__ row_ptr,
    int* __restrict__ wofs) {
  int i = blockIdx.x * 256 + threadIdx.x;
  if (i >= n) return;
  int val = psum[i] + bsum[blockIdx.x];
  row_ptr[i + 1] = val;
  wofs[i] = val - cnt[i];
}

__global__ __launch_bounds__(256) void scatter_k(
    const int* __restrict__ esrc, const int* __restrict__ edst,
    int E_real, int n_edges, int* __restrict__ wofs, int* __restrict__ csr_src) {
  int e = blockIdx.x * 256 + threadIdx.x;
  if (e >= n_edges) return;
  int s, d;
  if (e < E_real) { s = esrc[e]; d = edst[e]; } else { s = e - E_real; d = s; }
  int pos = atomicAdd(&wofs[d], 1);
  csr_src[pos] = s;
}

// ---------- fused GATv2 per-dst: score + online softmax + aggregate + selu ----------
// one 64-lane wave per dst node; lane h owns feature h
__global__ __launch_bounds__(256) void gat_dst(
    const int* __restrict__ row_ptr, const int* __restrict__ csr_src,
    const float* __restrict__ xl, const float* __restrict__ xr,
    const float* __restrict__ att, const float* __restrict__ bias,
    float* __restrict__ out, int n_dst) {
  int d = blockIdx.x * 4 + (threadIdx.x >> 6);
  if (d >= n_dst) return;
  int h = threadIdx.x & 63;
  float xr_h = xr[(size_t)d * H + h];
  float att_h = att[h];
  float bias_h = bias[h];
  int beg = row_ptr[d], end = row_ptr[d + 1];

  float m = -3.0e38f, s = 0.f, acc = 0.f;
  for (int i = beg; i < end; ++i) {
    int src = csr_src[i];
    float v = xl[(size_t)src * H + h];
    float p = v + xr_h;
    p = p > 0.f ? p : 0.2f * p;
    float t = p * att_h;
#pragma unroll
    for (int mk = 32; mk >= 1; mk >>= 1) t += __shfl_xor(t, mk, 64);
    float nm = fmaxf(m, t);
    float so = __expf(m - nm);   // 0 when m == -inf-ish, 1 when no new max
    float e = __expf(t - nm);
    s = s * so + e;
    acc = acc * so + e * v;
    m = nm;
  }
  float o = acc / (s + 1e-16f) + bias_h;
  out[(size_t)d * H + h] = selu_f(o);
}

// ---------- launch ----------
extern "C" void kernel_launch(void* const* d_in, const int* in_sizes, int n_in,
                              void* d_out, int out_size, void* d_ws, size_t ws_size,
                              hipStream_t stream) {
  const float* x_user = (const float*)d_in[0];
  const float* x_movie = (const float*)d_in[1];
  const int* e_u2m = (const int*)d_in[2];
  const int* e_m2u = (const int*)d_in[3];
  const float* Wl = (const float*)d_in[4];
  const float* bl = (const float*)d_in[5];
  const float* Wr = (const float*)d_in[6];
  const float* br = (const float*)d_in[7];
  const float* att = (const float*)d_in[8];
  const float* bias = (const float*)d_in[9];

  const int n_user = in_sizes[0] / H;
  const int n_movie = in_sizes[1] / H;
  const int E1 = in_sizes[2] / 2;  // user->movie
  const int E2 = in_sizes[3] / 2;  // movie->user
  const int n_loop = n_user < n_movie ? n_user : n_movie;
  const int nE1 = E1 + n_loop;
  const int nE2 = E2 + n_loop;

  float* ws = (float*)d_ws;
  size_t o = 0;
  float* xl_u2m = ws + o; o += (size_t)n_user * H;
  float* xr_u2m = ws + o; o += (size_t)n_movie * H;
  float* xl_m2u = ws + o; o += (size_t)n_movie * H;
  float* xr_m2u = ws + o; o += (size_t)n_user * H;

  // zero region: cnt1 | row_ptr1 | cnt2 | row_ptr2 (contiguous)
  size_t zero_base = o;
  int* cnt1 = (int*)(ws + o); o += n_movie;
  int* rp1  = (int*)(ws + o); o += n_movie + 1;
  int* cnt2 = (int*)(ws + o); o += n_user;
  int* rp2  = (int*)(ws + o); o += n_user + 1;
  const size_t zero_bytes = (o - zero_base) * sizeof(float);

  int* psum1 = (int*)(ws + o); o += n_movie;
  int* wofs1 = (int*)(ws + o); o += n_movie;
  int* psum2 = (int*)(ws + o); o += n_user;
  int* wofs2 = (int*)(ws + o); o += n_user;
  int* bsum1 = (int*)(ws + o); o += 1024;
  int* bsum2 = (int*)(ws + o); o += 1024;
  int* csr1  = (int*)(ws + o); o += nE1;
  int* csr2  = (int*)(ws + o); o += nE2;

  float* out_u = (float*)d_out;
  float* out_m = out_u + (size_t)n_user * H;

  const int gu = (n_user + 63) / 64;
  const int gm = (n_movie + 63) / 64;
  const int nb1 = (n_movie + 255) / 256;
  const int nb2 = (n_user + 255) / 256;

  // ---- CSR build (layer-invariant, once per launch) ----
  hipMemsetAsync(ws + zero_base, 0, zero_bytes, stream);
  hist_k<<<(nE1 + 255) / 256, 256, 0, stream>>>(e_u2m + E1, E1, nE1, cnt1);
  hist_k<<<(nE2 + 255) / 256, 256, 0, stream>>>(e_m2u + E2, E2, nE2, cnt2);
  scan_partial<<<nb1, 256, 0, stream>>>(cnt1, n_movie, psum1, bsum1);
  scan_partial<<<nb2, 256, 0, stream>>>(cnt2, n_user, psum2, bsum2);
  scan_bsums<<<1, 64, 0, stream>>>(bsum1, nb1);
  scan_bsums<<<1, 64, 0, stream>>>(bsum2, nb2);
  finalize_scan<<<nb1, 256, 0, stream>>>(cnt1, psum1, bsum1, n_movie, rp1, wofs1);
  finalize_scan<<<nb2, 256, 0, stream>>>(cnt2, psum2, bsum2, n_user, rp2, wofs2);
  scatter_k<<<(nE1 + 255) / 256, 256, 0, stream>>>(e_u2m, e_u2m + E1, E1, nE1, wofs1, csr1);
  scatter_k<<<(nE2 + 255) / 256, 256, 0, stream>>>(e_m2u, e_m2u + E2, E2, nE2, wofs2, csr2);

  for (int l = 0; l < 2; ++l) {
    const float* cu = (l == 0) ? x_user : out_u;
    const float* cm = (l == 0) ? x_movie : out_m;
    const int p0 = l * 2 + 0;  // user->movie
    const int p1 = l * 2 + 1;  // movie->user

    gemm64<<<gu, 256, 0, stream>>>(cu, Wl + (size_t)p0 * H * H, bl + (size_t)p0 * H, xl_u2m, n_user);
    gemm64<<<gm, 256, 0, stream>>>(cm, Wr + (size_t)p0 * H * H, br + (size_t)p0 * H, xr_u2m, n_movie);
    gemm64<<<gm, 256, 0, stream>>>(cm, Wl + (size_t)p1 * H * H, bl + (size_t)p1 * H, xl_m2u, n_movie);
    gemm64<<<gu, 256, 0, stream>>>(cu, Wr + (size_t)p1 * H * H, br + (size_t)p1 * H, xr_m2u, n_user);

    gat_dst<<<(n_movie + 3) / 4, 256, 0, stream>>>(
        rp1, csr1, xl_u2m, xr_u2m, att + (size_t)p0 * H, bias + (size_t)p0 * H, out_m, n_movie);
    gat_dst<<<(n_user + 3) / 4, 256, 0, stream>>>(
        rp2, csr2, xl_m2u, xr_m2u, att + (size_t)p1 * H, bias + (size_t)p1 * H, out_u, n_user);
  }
}

// Round 3
// 857.922 us; speedup vs baseline: 2.1555x; 1.1840x over previous
//
#include <hip/hip_runtime.h>
#include <cstdint>

#define H 64

__device__ __forceinline__ float selu_f(float x) {
  const float sc = 1.0507009873554805f;
  const float al = 1.6732632423543772f;
  return x > 0.f ? sc * x : sc * al * (expf(x) - 1.f);
}

// ---------- dual GEMM: C0 = A@W0+b0, C1 = A@W1+b1 (A staged once) ----------
// 256 thr = 64 rows x 4 col-groups(16). W0,W1 (32KB) + A tile (stride 65) in LDS.
__global__ __launch_bounds__(256) void gemm64_dual(
    const float* __restrict__ A,
    const float* __restrict__ W0, const float* __restrict__ b0,
    const float* __restrict__ W1, const float* __restrict__ b1,
    float* __restrict__ C0, float* __restrict__ C1, int N) {
  __shared__ float Ws0[64 * 64];
  __shared__ float Ws1[64 * 64];
  __shared__ float As[64][65];
  __shared__ float bs0[64], bs1[64];

  const int tid = threadIdx.x;
  for (int i = tid; i < 1024; i += 256) {
    ((float4*)Ws0)[i] = ((const float4*)W0)[i];
    ((float4*)Ws1)[i] = ((const float4*)W1)[i];
  }
  if (tid < 64) { bs0[tid] = b0[tid]; bs1[tid] = b1[tid]; }

  const int row0 = blockIdx.x * 64;
  for (int i = tid; i < 1024; i += 256) {
    int r = i >> 4, c4 = i & 15;
    int row = row0 + r;
    float4 v = make_float4(0.f, 0.f, 0.f, 0.f);
    if (row < N) v = ((const float4*)(A + (size_t)row * H))[c4];
    As[r][c4 * 4 + 0] = v.x;
    As[r][c4 * 4 + 1] = v.y;
    As[r][c4 * 4 + 2] = v.z;
    As[r][c4 * 4 + 3] = v.w;
  }
  __syncthreads();

  const int g = tid & 3;
  const int r = tid >> 2;
  float a0[16], a1[16];
#pragma unroll
  for (int j = 0; j < 16; ++j) { a0[j] = bs0[g * 16 + j]; a1[j] = bs1[g * 16 + j]; }

  for (int k = 0; k < 64; ++k) {
    float ak = As[r][k];
    const float4* w0r = (const float4*)&Ws0[k * 64 + g * 16];
    const float4* w1r = (const float4*)&Ws1[k * 64 + g * 16];
#pragma unroll
    for (int j4 = 0; j4 < 4; ++j4) {
      float4 w0 = w0r[j4], w1 = w1r[j4];
      a0[j4 * 4 + 0] += ak * w0.x; a0[j4 * 4 + 1] += ak * w0.y;
      a0[j4 * 4 + 2] += ak * w0.z; a0[j4 * 4 + 3] += ak * w0.w;
      a1[j4 * 4 + 0] += ak * w1.x; a1[j4 * 4 + 1] += ak * w1.y;
      a1[j4 * 4 + 2] += ak * w1.z; a1[j4 * 4 + 3] += ak * w1.w;
    }
  }

  const int row = row0 + r;
  if (row < N) {
    float4* c0 = (float4*)(C0 + (size_t)row * H + g * 16);
    float4* c1 = (float4*)(C1 + (size_t)row * H + g * 16);
#pragma unroll
    for (int j4 = 0; j4 < 4; ++j4) {
      c0[j4] = make_float4(a0[j4 * 4 + 0], a0[j4 * 4 + 1], a0[j4 * 4 + 2], a0[j4 * 4 + 3]);
      c1[j4] = make_float4(a1[j4 * 4 + 0], a1[j4 * 4 + 1], a1[j4 * 4 + 2], a1[j4 * 4 + 3]);
    }
  }
}

// ---------- CSR build ----------
__global__ __launch_bounds__(256) void hist_k(
    const int* __restrict__ edst, int E_real, int n_edges, int* __restrict__ cnt) {
  int e = blockIdx.x * 256 + threadIdx.x;
  if (e >= n_edges) return;
  int d = (e < E_real) ? edst[e] : (e - E_real);
  atomicAdd(&cnt[d], 1);
}

__global__ __launch_bounds__(256) void scan_partial(
    const int* __restrict__ cnt, int n, int* __restrict__ psum, int* __restrict__ bsum) {
  __shared__ int sh[256];
  int i = blockIdx.x * 256 + threadIdx.x;
  int tid = threadIdx.x;
  sh[tid] = (i < n) ? cnt[i] : 0;
  __syncthreads();
  for (int off = 1; off < 256; off <<= 1) {
    int t = (tid >= off) ? sh[tid - off] : 0;
    __syncthreads();
    if (tid >= off) sh[tid] += t;
    __syncthreads();
  }
  if (i < n) psum[i] = sh[tid];
  if (tid == 255) bsum[blockIdx.x] = sh[255];
}

// exclusive scan of bsum, single block, parallel
__global__ __launch_bounds__(256) void scan_bsums(int* __restrict__ bsum, int nb) {
  __shared__ int sh[256];
  const int tid = threadIdx.x;
  int run = 0;
  for (int start = 0; start < nb; start += 256) {
    int i = start + tid;
    int v = (i < nb) ? bsum[i] : 0;
    __syncthreads();
    sh[tid] = v;
    __syncthreads();
    for (int off = 1; off < 256; off <<= 1) {
      int t = (tid >= off) ? sh[tid - off] : 0;
      __syncthreads();
      if (tid >= off) sh[tid] += t;
      __syncthreads();
    }
    if (i < nb) bsum[i] = run + sh[tid] - v;  // exclusive
    run += sh[255];
  }
}

__global__ __launch_bounds__(256) void finalize_scan(
    const int* __restrict__ cnt, const int* __restrict__ psum,
    const int* __restrict__ bsum, int n, int* __restrict__ row_ptr,
    int* __restrict__ wofs) {
  int i = blockIdx.x * 256 + threadIdx.x;
  if (i >= n) return;
  int val = psum[i] + bsum[blockIdx.x];
  row_ptr[i + 1] = val;
  wofs[i] = val - cnt[i];
}

__global__ __launch_bounds__(256) void scatter_k(
    const int* __restrict__ esrc, const int* __restrict__ edst,
    int E_real, int n_edges, int* __restrict__ wofs, int* __restrict__ csr_src) {
  int e = blockIdx.x * 256 + threadIdx.x;
  if (e >= n_edges) return;
  int s, d;
  if (e < E_real) { s = esrc[e]; d = edst[e]; } else { s = e - E_real; d = s; }
  int pos = atomicAdd(&wofs[d], 1);
  csr_src[pos] = s;
}

// ---------- fused GATv2 per-dst: 8-way unrolled gathers + online softmax ----------
// one 64-lane wave per dst node; lane h owns feature h
__global__ __launch_bounds__(256) void gat_dst(
    const int* __restrict__ row_ptr, const int* __restrict__ csr_src,
    const float* __restrict__ xl, const float* __restrict__ xr,
    const float* __restrict__ att, const float* __restrict__ bias,
    float* __restrict__ out, int n_dst) {
  int d = blockIdx.x * 4 + (threadIdx.x >> 6);
  if (d >= n_dst) return;
  int h = threadIdx.x & 63;
  float xr_h = xr[(size_t)d * H + h];
  float att_h = att[h];
  float bias_h = bias[h];
  int beg = row_ptr[d], end = row_ptr[d + 1];

  float m = -3.0e38f, s = 0.f, acc = 0.f;
  for (int i = beg; i < end; i += 8) {
    const int cnt = end - i;  // >= 1, wave-uniform
    int sj[8];
#pragma unroll
    for (int k = 0; k < 8; ++k) {
      int j = i + k;
      sj[k] = csr_src[j < end ? j : end - 1];
    }
    float v[8];
#pragma unroll
    for (int k = 0; k < 8; ++k) v[k] = xl[(size_t)sj[k] * H + h];  // 8 indep gathers
#pragma unroll
    for (int k = 0; k < 8; ++k) {
      if (k < cnt) {  // wave-uniform branch
        float p = v[k] + xr_h;
        p = p > 0.f ? p : 0.2f * p;
        float t = p * att_h;
#pragma unroll
        for (int mk = 32; mk >= 1; mk >>= 1) t += __shfl_xor(t, mk, 64);
        float nm = fmaxf(m, t);
        float so = __expf(m - nm);
        float e = __expf(t - nm);
        s = s * so + e;
        acc = acc * so + e * v[k];
        m = nm;
      }
    }
  }
  float o = acc / (s + 1e-16f) + bias_h;
  out[(size_t)d * H + h] = selu_f(o);
}

// ---------- launch ----------
extern "C" void kernel_launch(void* const* d_in, const int* in_sizes, int n_in,
                              void* d_out, int out_size, void* d_ws, size_t ws_size,
                              hipStream_t stream) {
  const float* x_user = (const float*)d_in[0];
  const float* x_movie = (const float*)d_in[1];
  const int* e_u2m = (const int*)d_in[2];
  const int* e_m2u = (const int*)d_in[3];
  const float* Wl = (const float*)d_in[4];
  const float* bl = (const float*)d_in[5];
  const float* Wr = (const float*)d_in[6];
  const float* br = (const float*)d_in[7];
  const float* att = (const float*)d_in[8];
  const float* bias = (const float*)d_in[9];

  const int n_user = in_sizes[0] / H;
  const int n_movie = in_sizes[1] / H;
  const int E1 = in_sizes[2] / 2;  // user->movie
  const int E2 = in_sizes[3] / 2;  // movie->user
  const int n_loop = n_user < n_movie ? n_user : n_movie;
  const int nE1 = E1 + n_loop;
  const int nE2 = E2 + n_loop;

  float* ws = (float*)d_ws;
  size_t o = 0;
  float* xl_u2m = ws + o; o += (size_t)n_user * H;
  float* xr_u2m = ws + o; o += (size_t)n_movie * H;
  float* xl_m2u = ws + o; o += (size_t)n_movie * H;
  float* xr_m2u = ws + o; o += (size_t)n_user * H;

  // zero region: cnt1 | row_ptr1 | cnt2 | row_ptr2 (contiguous)
  size_t zero_base = o;
  int* cnt1 = (int*)(ws + o); o += n_movie;
  int* rp1  = (int*)(ws + o); o += n_movie + 1;
  int* cnt2 = (int*)(ws + o); o += n_user;
  int* rp2  = (int*)(ws + o); o += n_user + 1;
  const size_t zero_bytes = (o - zero_base) * sizeof(float);

  int* psum1 = (int*)(ws + o); o += n_movie;
  int* wofs1 = (int*)(ws + o); o += n_movie;
  int* psum2 = (int*)(ws + o); o += n_user;
  int* wofs2 = (int*)(ws + o); o += n_user;
  int* bsum1 = (int*)(ws + o); o += 1024;
  int* bsum2 = (int*)(ws + o); o += 1024;
  int* csr1  = (int*)(ws + o); o += nE1;
  int* csr2  = (int*)(ws + o); o += nE2;

  float* out_u = (float*)d_out;
  float* out_m = out_u + (size_t)n_user * H;

  const int gu = (n_user + 63) / 64;
  const int gm = (n_movie + 63) / 64;
  const int nb1 = (n_movie + 255) / 256;
  const int nb2 = (n_user + 255) / 256;

  // ---- CSR build (layer-invariant, once per launch) ----
  hipMemsetAsync(ws + zero_base, 0, zero_bytes, stream);
  hist_k<<<(nE1 + 255) / 256, 256, 0, stream>>>(e_u2m + E1, E1, nE1, cnt1);
  hist_k<<<(nE2 + 255) / 256, 256, 0, stream>>>(e_m2u + E2, E2, nE2, cnt2);
  scan_partial<<<nb1, 256, 0, stream>>>(cnt1, n_movie, psum1, bsum1);
  scan_partial<<<nb2, 256, 0, stream>>>(cnt2, n_user, psum2, bsum2);
  scan_bsums<<<1, 256, 0, stream>>>(bsum1, nb1);
  scan_bsums<<<1, 256, 0, stream>>>(bsum2, nb2);
  finalize_scan<<<nb1, 256, 0, stream>>>(cnt1, psum1, bsum1, n_movie, rp1, wofs1);
  finalize_scan<<<nb2, 256, 0, stream>>>(cnt2, psum2, bsum2, n_user, rp2, wofs2);
  scatter_k<<<(nE1 + 255) / 256, 256, 0, stream>>>(e_u2m, e_u2m + E1, E1, nE1, wofs1, csr1);
  scatter_k<<<(nE2 + 255) / 256, 256, 0, stream>>>(e_m2u, e_m2u + E2, E2, nE2, wofs2, csr2);

  for (int l = 0; l < 2; ++l) {
    const float* cu = (l == 0) ? x_user : out_u;
    const float* cm = (l == 0) ? x_movie : out_m;
    const int p0 = l * 2 + 0;  // user->movie params
    const int p1 = l * 2 + 1;  // movie->user params

    // user rows: xl for u2m (Wl[p0]), xr for m2u (Wr[p1])
    gemm64_dual<<<gu, 256, 0, stream>>>(
        cu, Wl + (size_t)p0 * H * H, bl + (size_t)p0 * H,
        Wr + (size_t)p1 * H * H, br + (size_t)p1 * H, xl_u2m, xr_m2u, n_user);
    // movie rows: xr for u2m (Wr[p0]), xl for m2u (Wl[p1])
    gemm64_dual<<<gm, 256, 0, stream>>>(
        cm, Wr + (size_t)p0 * H * H, br + (size_t)p0 * H,
        Wl + (size_t)p1 * H * H, bl + (size_t)p1 * H, xr_u2m, xl_m2u, n_movie);

    gat_dst<<<(n_movie + 3) / 4, 256, 0, stream>>>(
        rp1, csr1, xl_u2m, xr_u2m, att + (size_t)p0 * H, bias + (size_t)p0 * H, out_m, n_movie);
    gat_dst<<<(n_user + 3) / 4, 256, 0, stream>>>(
        rp2, csr2, xl_m2u, xr_m2u, att + (size_t)p1 * H, bias + (size_t)p1 * H, out_u, n_user);
  }
}

// Round 4
// 733.349 us; speedup vs baseline: 2.5217x; 1.1699x over previous
//
#include <hip/hip_runtime.h>
#include <cstdint>

#define H 64
#define EPR 32  // edges per round in gat_dst

__device__ __forceinline__ float selu_f(float x) {
  const float sc = 1.0507009873554805f;
  const float al = 1.6732632423543772f;
  return x > 0.f ? sc * x : sc * al * (expf(x) - 1.f);
}

// ---------- dual GEMM: C0 = A@W0+b0, C1 = A@W1+b1 (A staged once) ----------
__global__ __launch_bounds__(256) void gemm64_dual(
    const float* __restrict__ A,
    const float* __restrict__ W0, const float* __restrict__ b0,
    const float* __restrict__ W1, const float* __restrict__ b1,
    float* __restrict__ C0, float* __restrict__ C1, int N) {
  __shared__ float Ws0[64 * 64];
  __shared__ float Ws1[64 * 64];
  __shared__ float As[64][65];
  __shared__ float bs0[64], bs1[64];

  const int tid = threadIdx.x;
  for (int i = tid; i < 1024; i += 256) {
    ((float4*)Ws0)[i] = ((const float4*)W0)[i];
    ((float4*)Ws1)[i] = ((const float4*)W1)[i];
  }
  if (tid < 64) { bs0[tid] = b0[tid]; bs1[tid] = b1[tid]; }

  const int row0 = blockIdx.x * 64;
  for (int i = tid; i < 1024; i += 256) {
    int r = i >> 4, c4 = i & 15;
    int row = row0 + r;
    float4 v = make_float4(0.f, 0.f, 0.f, 0.f);
    if (row < N) v = ((const float4*)(A + (size_t)row * H))[c4];
    As[r][c4 * 4 + 0] = v.x;
    As[r][c4 * 4 + 1] = v.y;
    As[r][c4 * 4 + 2] = v.z;
    As[r][c4 * 4 + 3] = v.w;
  }
  __syncthreads();

  const int g = tid & 3;
  const int r = tid >> 2;
  float a0[16], a1[16];
#pragma unroll
  for (int j = 0; j < 16; ++j) { a0[j] = bs0[g * 16 + j]; a1[j] = bs1[g * 16 + j]; }

  for (int k = 0; k < 64; ++k) {
    float ak = As[r][k];
    const float4* w0r = (const float4*)&Ws0[k * 64 + g * 16];
    const float4* w1r = (const float4*)&Ws1[k * 64 + g * 16];
#pragma unroll
    for (int j4 = 0; j4 < 4; ++j4) {
      float4 w0 = w0r[j4], w1 = w1r[j4];
      a0[j4 * 4 + 0] += ak * w0.x; a0[j4 * 4 + 1] += ak * w0.y;
      a0[j4 * 4 + 2] += ak * w0.z; a0[j4 * 4 + 3] += ak * w0.w;
      a1[j4 * 4 + 0] += ak * w1.x; a1[j4 * 4 + 1] += ak * w1.y;
      a1[j4 * 4 + 2] += ak * w1.z; a1[j4 * 4 + 3] += ak * w1.w;
    }
  }

  const int row = row0 + r;
  if (row < N) {
    float4* c0 = (float4*)(C0 + (size_t)row * H + g * 16);
    float4* c1 = (float4*)(C1 + (size_t)row * H + g * 16);
#pragma unroll
    for (int j4 = 0; j4 < 4; ++j4) {
      c0[j4] = make_float4(a0[j4 * 4 + 0], a0[j4 * 4 + 1], a0[j4 * 4 + 2], a0[j4 * 4 + 3]);
      c1[j4] = make_float4(a1[j4 * 4 + 0], a1[j4 * 4 + 1], a1[j4 * 4 + 2], a1[j4 * 4 + 3]);
    }
  }
}

// ---------- CSR build (dual-graph merged kernels) ----------
__global__ __launch_bounds__(256) void hist2_k(
    const int* __restrict__ ed1, int E1r, int n1e, int* __restrict__ c1,
    const int* __restrict__ ed2, int E2r, int n2e, int* __restrict__ c2,
    int split) {
  int b = blockIdx.x;
  const int* ed; int Er, ne; int* cnt; int e;
  if (b < split) { ed = ed1; Er = E1r; ne = n1e; cnt = c1; e = b * 256 + threadIdx.x; }
  else { ed = ed2; Er = E2r; ne = n2e; cnt = c2; e = (b - split) * 256 + threadIdx.x; }
  if (e >= ne) return;
  int d = (e < Er) ? ed[e] : (e - Er);
  atomicAdd(&cnt[d], 1);
}

__global__ __launch_bounds__(256) void scan_partial2(
    const int* __restrict__ cnt1, int n1, int* __restrict__ psum1, int* __restrict__ bsum1,
    const int* __restrict__ cnt2, int n2, int* __restrict__ psum2, int* __restrict__ bsum2,
    int split) {
  __shared__ int sh[256];
  int b = blockIdx.x;
  const int* cnt; int n; int* psum; int* bsum; int lb;
  if (b < split) { cnt = cnt1; n = n1; psum = psum1; bsum = bsum1; lb = b; }
  else { cnt = cnt2; n = n2; psum = psum2; bsum = bsum2; lb = b - split; }
  int i = lb * 256 + threadIdx.x;
  int tid = threadIdx.x;
  sh[tid] = (i < n) ? cnt[i] : 0;
  __syncthreads();
  for (int off = 1; off < 256; off <<= 1) {
    int t = (tid >= off) ? sh[tid - off] : 0;
    __syncthreads();
    if (tid >= off) sh[tid] += t;
    __syncthreads();
  }
  if (i < n) psum[i] = sh[tid];
  if (tid == 255) bsum[lb] = sh[255];
}

// exclusive scan of both bsum arrays, single block
__global__ __launch_bounds__(256) void scan_bsums2(
    int* __restrict__ bsum1, int nb1, int* __restrict__ bsum2, int nb2) {
  __shared__ int sh[256];
  const int tid = threadIdx.x;
  for (int which = 0; which < 2; ++which) {
    int* bsum = which ? bsum2 : bsum1;
    int nb = which ? nb2 : nb1;
    int run = 0;
    for (int start = 0; start < nb; start += 256) {
      int i = start + tid;
      int v = (i < nb) ? bsum[i] : 0;
      __syncthreads();
      sh[tid] = v;
      __syncthreads();
      for (int off = 1; off < 256; off <<= 1) {
        int t = (tid >= off) ? sh[tid - off] : 0;
        __syncthreads();
        if (tid >= off) sh[tid] += t;
        __syncthreads();
      }
      if (i < nb) bsum[i] = run + sh[tid] - v;  // exclusive
      run += sh[255];
      __syncthreads();
    }
  }
}

__global__ __launch_bounds__(256) void finalize_scan2(
    const int* __restrict__ cnt1, const int* __restrict__ psum1,
    const int* __restrict__ bsum1, int n1, int* __restrict__ rp1, int* __restrict__ wofs1,
    const int* __restrict__ cnt2, const int* __restrict__ psum2,
    const int* __restrict__ bsum2, int n2, int* __restrict__ rp2, int* __restrict__ wofs2,
    int split) {
  int b = blockIdx.x;
  const int *cnt, *psum, *bsum; int n; int *rp, *wofs; int lb;
  if (b < split) { cnt = cnt1; psum = psum1; bsum = bsum1; n = n1; rp = rp1; wofs = wofs1; lb = b; }
  else { cnt = cnt2; psum = psum2; bsum = bsum2; n = n2; rp = rp2; wofs = wofs2; lb = b - split; }
  int i = lb * 256 + threadIdx.x;
  if (i >= n) return;
  int val = psum[i] + bsum[lb];
  rp[i + 1] = val;
  wofs[i] = val - cnt[i];
}

__global__ __launch_bounds__(256) void scatter2_k(
    const int* __restrict__ es1, const int* __restrict__ ed1, int E1r, int n1e,
    int* __restrict__ wofs1, int* __restrict__ csr1,
    const int* __restrict__ es2, const int* __restrict__ ed2, int E2r, int n2e,
    int* __restrict__ wofs2, int* __restrict__ csr2, int split) {
  int b = blockIdx.x;
  const int *es, *ed; int Er, ne; int *wofs, *csr; int e;
  if (b < split) { es = es1; ed = ed1; Er = E1r; ne = n1e; wofs = wofs1; csr = csr1; e = b * 256 + threadIdx.x; }
  else { es = es2; ed = ed2; Er = E2r; ne = n2e; wofs = wofs2; csr = csr2; e = (b - split) * 256 + threadIdx.x; }
  if (e >= ne) return;
  int s, d;
  if (e < Er) { s = es[e]; d = ed[e]; } else { s = e - Er; d = s; }
  int pos = atomicAdd(&wofs[d], 1);
  csr[pos] = s;
}

// ---------- fused GATv2: one dst per 64-thread block ----------
// Phase 1 (lane=feature): gather rows, score contributions into swizzled LDS tile.
// Transpose (lane=edge): batched score reduce + softmax butterflies per 32 edges.
// Phase 2 (lane=feature): weighted sum from register-held rows, flash-style merge.
__global__ __launch_bounds__(64) void gat_dst(
    const int* __restrict__ row_ptr, const int* __restrict__ csr_src,
    const float* __restrict__ xl, const float* __restrict__ xr,
    const float* __restrict__ att, const float* __restrict__ bias,
    float* __restrict__ out, int n_dst) {
  __shared__ __align__(16) float tile[EPR * 64];  // 8 KB, xor-swizzled columns

  const int d = blockIdx.x;
  const int h = threadIdx.x;  // 0..63
  const float xr_h = xr[(size_t)d * H + h];
  const float att_h = att[h];
  const int beg = row_ptr[d];
  const int end = row_ptr[d + 1];

  const int hx = h << 2;                              // byte col before swizzle
  const int tr = h & 31;                              // transpose: my edge row
  const int trbase = (tr << 8) ^ ((tr & 15) << 4);    // swizzled row base (bytes)
  const int tro = (h >> 5) * 8;                       // half-row chunk start

  float m = -3.0e38f, s = 0.f, acc = 0.f;

  for (int base = beg; base < end; base += EPR) {
    int cnt = end - base;
    if (cnt > EPR) cnt = EPR;
    float v[EPR];

    // ---- phase 1: coalesced row gathers + score contributions ----
#pragma unroll
    for (int q = 0; q < EPR / 4; ++q) {
      if (q * 4 < cnt) {  // wave-uniform
#pragma unroll
        for (int i = 0; i < 4; ++i) {
          const int k = q * 4 + i;
          int j = k < cnt ? k : cnt - 1;     // clamped dup (harmless overwrite)
          int src = csr_src[base + j];       // wave-uniform -> scalar load
          float vv = xl[(size_t)src * H + h];
          v[k] = vv;
          float p = vv + xr_h;
          p = fmaxf(p, 0.f) + 0.2f * fminf(p, 0.f);  // leaky relu
          *(float*)((char*)tile + (k << 8) + (hx ^ ((k & 15) << 4))) = p * att_h;
        }
      }
    }

    // ---- transpose read: per-edge score, half-row per lane ----
    float t0 = 0.f, t1 = 0.f, t2 = 0.f, t3 = 0.f;
#pragma unroll
    for (int c = 0; c < 8; ++c) {
      float4 q4 = *(const float4*)((const char*)tile + (trbase ^ ((tro + c) << 4)));
      t0 += q4.x; t1 += q4.y; t2 += q4.z; t3 += q4.w;
    }
    float t = (t0 + t1) + (t2 + t3);
    t += __shfl_xor(t, 32, 64);          // combine the two half-rows
    t = (tr < cnt) ? t : -3.0e38f;       // mask invalid edges (kills stale/NaN)

    // ---- batched softmax over this round's <=32 edges ----
    float M = t;
#pragma unroll
    for (int mk = 1; mk <= 16; mk <<= 1) M = fmaxf(M, __shfl_xor(M, mk, 64));
    float e = __expf(t - M);             // 0 for masked lanes
    float S = e;
#pragma unroll
    for (int mk = 1; mk <= 16; mk <<= 1) S += __shfl_xor(S, mk, 64);
    if (h < 32) tile[h] = e;             // w_k into consumed tile row 0

    // ---- flash-style merge + phase 2 weighted sum ----
    float nm = fmaxf(m, M);
    float a_old = __expf(m - nm);
    float a_new = __expf(M - nm);
    float P = 0.f;
#pragma unroll
    for (int q = 0; q < EPR / 4; ++q) {
      if (q * 4 < cnt) {  // wave-uniform; w==0 for k>=cnt, v finite (dup)
        float4 w4 = ((const float4*)tile)[q];  // broadcast read
        P += w4.x * v[q * 4 + 0];
        P += w4.y * v[q * 4 + 1];
        P += w4.z * v[q * 4 + 2];
        P += w4.w * v[q * 4 + 3];
      }
    }
    s = s * a_old + S * a_new;
    acc = acc * a_old + P * a_new;
    m = nm;
  }

  float o = acc / (s + 1e-16f) + bias[h];
  out[(size_t)d * H + h] = selu_f(o);
}

// ---------- launch ----------
extern "C" void kernel_launch(void* const* d_in, const int* in_sizes, int n_in,
                              void* d_out, int out_size, void* d_ws, size_t ws_size,
                              hipStream_t stream) {
  const float* x_user = (const float*)d_in[0];
  const float* x_movie = (const float*)d_in[1];
  const int* e_u2m = (const int*)d_in[2];
  const int* e_m2u = (const int*)d_in[3];
  const float* Wl = (const float*)d_in[4];
  const float* bl = (const float*)d_in[5];
  const float* Wr = (const float*)d_in[6];
  const float* br = (const float*)d_in[7];
  const float* att = (const float*)d_in[8];
  const float* bias = (const float*)d_in[9];

  const int n_user = in_sizes[0] / H;
  const int n_movie = in_sizes[1] / H;
  const int E1 = in_sizes[2] / 2;  // user->movie
  const int E2 = in_sizes[3] / 2;  // movie->user
  const int n_loop = n_user < n_movie ? n_user : n_movie;
  const int nE1 = E1 + n_loop;
  const int nE2 = E2 + n_loop;

  float* ws = (float*)d_ws;
  size_t o = 0;
  float* xl_u2m = ws + o; o += (size_t)n_user * H;
  float* xr_u2m = ws + o; o += (size_t)n_movie * H;
  float* xl_m2u = ws + o; o += (size_t)n_movie * H;
  float* xr_m2u = ws + o; o += (size_t)n_user * H;

  // zero region: cnt1 | row_ptr1 | cnt2 | row_ptr2 (contiguous)
  size_t zero_base = o;
  int* cnt1 = (int*)(ws + o); o += n_movie;
  int* rp1  = (int*)(ws + o); o += n_movie + 1;
  int* cnt2 = (int*)(ws + o); o += n_user;
  int* rp2  = (int*)(ws + o); o += n_user + 1;
  const size_t zero_bytes = (o - zero_base) * sizeof(float);

  int* psum1 = (int*)(ws + o); o += n_movie;
  int* wofs1 = (int*)(ws + o); o += n_movie;
  int* psum2 = (int*)(ws + o); o += n_user;
  int* wofs2 = (int*)(ws + o); o += n_user;
  int* bsum1 = (int*)(ws + o); o += 1024;
  int* bsum2 = (int*)(ws + o); o += 1024;
  int* csr1  = (int*)(ws + o); o += nE1;
  int* csr2  = (int*)(ws + o); o += nE2;

  float* out_u = (float*)d_out;
  float* out_m = out_u + (size_t)n_user * H;

  const int gu = (n_user + 63) / 64;
  const int gm = (n_movie + 63) / 64;
  const int nb1 = (n_movie + 255) / 256;
  const int nb2 = (n_user + 255) / 256;
  const int ebe1 = (nE1 + 255) / 256;
  const int ebe2 = (nE2 + 255) / 256;

  // ---- CSR build (layer-invariant, once per launch, merged dual-graph) ----
  hipMemsetAsync(ws + zero_base, 0, zero_bytes, stream);
  hist2_k<<<ebe1 + ebe2, 256, 0, stream>>>(
      e_u2m + E1, E1, nE1, cnt1, e_m2u + E2, E2, nE2, cnt2, ebe1);
  scan_partial2<<<nb1 + nb2, 256, 0, stream>>>(
      cnt1, n_movie, psum1, bsum1, cnt2, n_user, psum2, bsum2, nb1);
  scan_bsums2<<<1, 256, 0, stream>>>(bsum1, nb1, bsum2, nb2);
  finalize_scan2<<<nb1 + nb2, 256, 0, stream>>>(
      cnt1, psum1, bsum1, n_movie, rp1, wofs1,
      cnt2, psum2, bsum2, n_user, rp2, wofs2, nb1);
  scatter2_k<<<ebe1 + ebe2, 256, 0, stream>>>(
      e_u2m, e_u2m + E1, E1, nE1, wofs1, csr1,
      e_m2u, e_m2u + E2, E2, nE2, wofs2, csr2, ebe1);

  for (int l = 0; l < 2; ++l) {
    const float* cu = (l == 0) ? x_user : out_u;
    const float* cm = (l == 0) ? x_movie : out_m;
    const int p0 = l * 2 + 0;  // user->movie params
    const int p1 = l * 2 + 1;  // movie->user params

    gemm64_dual<<<gu, 256, 0, stream>>>(
        cu, Wl + (size_t)p0 * H * H, bl + (size_t)p0 * H,
        Wr + (size_t)p1 * H * H, br + (size_t)p1 * H, xl_u2m, xr_m2u, n_user);
    gemm64_dual<<<gm, 256, 0, stream>>>(
        cm, Wr + (size_t)p0 * H * H, br + (size_t)p0 * H,
        Wl + (size_t)p1 * H * H, bl + (size_t)p1 * H, xr_u2m, xl_m2u, n_movie);

    gat_dst<<<n_movie, 64, 0, stream>>>(
        rp1, csr1, xl_u2m, xr_u2m, att + (size_t)p0 * H, bias + (size_t)p0 * H, out_m, n_movie);
    gat_dst<<<n_user, 64, 0, stream>>>(
        rp2, csr2, xl_m2u, xr_m2u, att + (size_t)p1 * H, bias + (size_t)p1 * H, out_u, n_user);
  }
}